// Round 9
// baseline (248.278 us; speedup 1.0000x reference)
//
#include <hip/hip_runtime.h>

// LIF forward: x [B=32, T=16, N=65536] f32, thresh scalar f32 -> spikes [B,T,N] f32
//   mem = mem*TAU + x[t];  spike = (mem > thresh);  mem = spike ? 0 : mem;
//
// History: R1-R7 register-destination loads all stuck at ~80 us / 2.5 TB/s
// (VGPR 20-24, ~2 loads in flight; every pinning trick defeated). R8 bulk
// global_load_lds + vmcnt(0): still ~79 us (inferred from total-overhead
// decomposition) -> burst MLP isn't enough.
// R9: persistent double-buffered pipeline, zero barriers:
//   - 512 blocks = exactly 2/CU (64 KB LDS each), no block turnover.
//   - each block: 8 chunks of [16 t][512 floats]; while computing chunk c
//     from lds[buf], 32 DMAs prefetch chunk c+1 into lds[buf^1].
//   - counted s_waitcnt vmcnt(32): only the newest 32 (the prefetch) may
//     remain outstanding -> current chunk's data guaranteed, reads NEVER
//     drain to zero in flight (64 KB/CU continuous - m13 saturates at ~32).
//   - DMA region per wave == compute region per wave -> no __syncthreads.
//   - safety: compute_c's ds_reads complete before stage(c+2) reuses the
//     buffer (store data-depends on loaded values -> lgkmcnt drained).

#define TAU 0.25f

typedef float f32x2 __attribute__((ext_vector_type(2)));

__device__ __forceinline__ void stage_chunk(
    const float* __restrict__ gbase,   // x + xbase + c*TILE  (per-block)
    float* __restrict__ lbase,         // &lds[buf][0][0]
    int w, int lane)
{
    constexpr int N = 65536;
#pragma unroll
    for (int t = 0; t < 16; ++t) {
#pragma unroll
        for (int h = 0; h < 2; ++h) {
            const float* gsrc = gbase + (size_t)t * N + w * 128 + h * 64 + lane;
            float*       ldst = lbase + t * 512 + w * 128 + h * 64;
            __builtin_amdgcn_global_load_lds(
                (const __attribute__((address_space(1))) void*)gsrc,
                (__attribute__((address_space(3))) void*)ldst,
                4, 0, 0);   // 4 B/lane x 64 lanes = 256 B contiguous per instr
        }
    }
}

__global__ __launch_bounds__(256) void lif_fwd_kernel(
    const float* __restrict__ x,
    const float* __restrict__ thresh,
    float* __restrict__ out)
{
    constexpr int T      = 16;
    constexpr int N      = 65536;
    constexpr int TILE   = 512;   // floats per t per chunk
    constexpr int CHUNKS = 8;     // per block: n-range = 4096 floats

    __shared__ float lds[2][T][TILE];   // 64 KB -> 2 blocks/CU, 8 waves/CU

    const int tid  = threadIdx.x;
    const int w    = tid >> 6;
    const int lane = tid & 63;

    const int b  = blockIdx.x >> 4;     // 32 b
    const int nb = blockIdx.x & 15;     // 16 n-blocks per b
    const size_t xbase = (size_t)b * T * N + (size_t)nb * (CHUNKS * TILE);

    const float th  = thresh[0];
    const int   col = w * 128 + lane * 2;   // this thread's f32x2 within TILE

    // Prologue: stage chunk 0.
    stage_chunk(x + xbase, &lds[0][0][0], w, lane);

    for (int c = 0; c < CHUNKS; ++c) {
        const int buf = c & 1;

        if (c + 1 < CHUNKS) {
            // Prefetch next chunk into the other buffer (wave-private region).
            stage_chunk(x + xbase + (size_t)(c + 1) * TILE,
                        &lds[buf ^ 1][0][0], w, lane);
            // Newest 32 VMEM ops = the prefetch; everything older (this
            // chunk's DMAs + last chunk's stores) must be complete.
            asm volatile("s_waitcnt vmcnt(32)" ::: "memory");
        } else {
            asm volatile("s_waitcnt vmcnt(0)" ::: "memory");
        }
        __builtin_amdgcn_sched_barrier(0);

        float mx = 0.f, my = 0.f;
        const float* lp = &lds[buf][0][0];
        float*       gp = out + xbase + (size_t)c * TILE;

#pragma unroll
        for (int t = 0; t < T; ++t) {
            f32x2 xt = *(const f32x2*)(lp + t * TILE + col);   // ds_read_b64

            mx = mx * TAU + xt.x;
            my = my * TAU + xt.y;

            const bool px = mx > th;
            const bool py = my > th;

            f32x2 s;
            s.x = px ? 1.f : 0.f;
            s.y = py ? 1.f : 0.f;

            mx = px ? 0.f : mx;
            my = py ? 0.f : my;

            // Output never re-read: keep L2/L3 for the x stream.
            __builtin_nontemporal_store(s, (f32x2*)(gp + (size_t)t * N + col));
        }
    }
}

extern "C" void kernel_launch(void* const* d_in, const int* in_sizes, int n_in,
                              void* d_out, int out_size, void* d_ws, size_t ws_size,
                              hipStream_t stream)
{
    const float* x      = (const float*)d_in[0];
    const float* thresh = (const float*)d_in[1];
    float*       out    = (float*)d_out;

    // total = 33,554,432 elems; per block = 16 t * 4096 n = 65536 -> 512 blocks
    const int total = in_sizes[0];
    const int grid  = total / (16 * 4096);   // 512
    const int block = 256;

    lif_fwd_kernel<<<grid, block, 0, stream>>>(x, thresh, out);
}